// Round 5
// baseline (280.325 us; speedup 1.0000x reference)
//
#include <hip/hip_runtime.h>
#include <math.h>

#define CHUNK 256
#define FPS 32768.0f   // fixed-point scale 2^15 for transition sums

// K1: nh[n][t] = x[n].v[:,t]. One thread per node, 32 outputs via float4.
__global__ __launch_bounds__(256) void nh_kernel(const float* __restrict__ x,
    const float* __restrict__ v, float* __restrict__ nh, int N) {
  __shared__ float vs[96];
  int tid = threadIdx.x;
  if (tid < 96) vs[tid] = v[tid];
  __syncthreads();
  int n = blockIdx.x * 256 + tid;
  if (n >= N) return;
  float x0 = x[3 * n], x1 = x[3 * n + 1], x2 = x[3 * n + 2];
  float4* row = (float4*)(nh + (size_t)n * 32);
#pragma unroll
  for (int i = 0; i < 8; ++i) {
    float4 r;
    r.x = fmaf(x0, vs[4 * i + 0], fmaf(x1, vs[32 + 4 * i + 0], x2 * vs[64 + 4 * i + 0]));
    r.y = fmaf(x0, vs[4 * i + 1], fmaf(x1, vs[32 + 4 * i + 1], x2 * vs[64 + 4 * i + 1]));
    r.z = fmaf(x0, vs[4 * i + 2], fmaf(x1, vs[32 + 4 * i + 2], x2 * vs[64 + 4 * i + 2]));
    r.w = fmaf(x0, vs[4 * i + 3], fmaf(x1, vs[32 + 4 * i + 3], x2 * vs[64 + 4 * i + 3]));
    row[i] = r;
  }
}

// K2: bucket-scatter by graph. Per-wave ballot ranks; one global atomicAdd per
// (wave, graph) reserves a slot range in the fixed per-graph bucket g*M.
// Placement order across waves is nondeterministic — harmless, because all
// downstream accumulation is integer (order-independent).
__global__ __launch_bounds__(256) void scatter_kernel(const int* __restrict__ ei,
    const int* __restrict__ face, const int* __restrict__ batch,
    int* __restrict__ sorted, int* __restrict__ cnt8, int N, int E, int F, int M) {
  int tid = threadIdx.x;
  int m = blockIdx.x * 256 + tid;
  int g = -1;
  if (m < M) {
    if (m < N) g = batch[m];
    else if (m < N + E) g = batch[ei[m - N]];
    else g = batch[face[m - N - E]];
  }
  int lane = tid & 63;
  unsigned long long below = (1ull << lane) - 1ull;
  int rank = 0, basereg = 0;
#pragma unroll
  for (int gg = 0; gg < 8; ++gg) {
    unsigned long long mm = __ballot(g == gg);
    if (g == gg) rank = __popcll(mm & below);
    if (lane == gg && mm) basereg = atomicAdd(&cnt8[gg], __popcll(mm));
  }
  int mybase = __shfl(basereg, g < 0 ? 0 : g);
  if (g >= 0) sorted[g * M + mybase + rank] = m;
}

// K3: saturation-split ECT. Block = (graph, chunk), self-derived from cnt8.
// Transition bins (<=2 per (m,theta)) get a sigmoid in 2^15 fixed point; the
// saturated region is one integer marker at bin fs (prefix-summed in fin).
// Flush: int atomics into global gcnt/gacc — deterministic by associativity.
__global__ __launch_bounds__(256) void ect_kernel(const float* __restrict__ nh,
    const int* __restrict__ ei, const int* __restrict__ face,
    const int* __restrict__ sorted, const int* __restrict__ cnt8,
    const float* __restrict__ lin, const int* __restrict__ scale_p,
    int* __restrict__ gcnt, int* __restrict__ gacc, int N, int E, int F, int M) {
  __shared__ int acc[32][32];   // [bin][theta] fixed-point transition sums
  __shared__ int cnt[32][32];   // [bin][theta] saturated-region markers
  int tid = threadIdx.x, bid = blockIdx.x;
  int c8[8];
#pragma unroll
  for (int gg = 0; gg < 8; ++gg) c8[gg] = cnt8[gg];
  int g = -1, c = 0, tc = 0;
#pragma unroll
  for (int gg = 0; gg < 8; ++gg) {
    int nch = (c8[gg] + CHUNK - 1) / CHUNK;
    if (bid >= tc && bid < tc + nch) { g = gg; c = bid - tc; }
    tc += nch;
  }
  if (g < 0) return;
  for (int i = tid; i < 1024; i += 256) { ((int*)acc)[i] = 0; ((int*)cnt)[i] = 0; }
  __syncthreads();

  int start = g * M + c * CHUNK;
  int nrem = min(CHUNK, c8[g] - c * CHUNK);
  int t = tid & 31, srow = tid >> 5;

  float scale = (float)scale_p[0];
  float lin0 = lin[0];
  float step = (lin[31] - lin0) * (1.f / 31.f);
  float istep = 1.f / step;
  float Cl = scale * step * 1.44269504088896f;  // log2-slope per bin
  float w = 25.f / (scale * step);              // transition half-width in bins

  for (int idx = srow; idx < nrem; idx += 8) {
    int m = sorted[start + idx];
    float h;
    int isn;
    if (m < N) {
      h = nh[(size_t)m * 32 + t];
      isn = 1;
    } else if (m < N + E) {
      int e = m - N;
      h = fmaxf(nh[(size_t)ei[e] * 32 + t], nh[(size_t)ei[E + e] * 32 + t]);
      isn = -1;
    } else {
      int f = m - N - E;
      h = fmaxf(fmaxf(nh[(size_t)face[f] * 32 + t],
                      nh[(size_t)face[F + f] * 32 + t]),
                nh[(size_t)face[2 * F + f] * 32 + t]);
      isn = 1;
    }
    float kf = (h - lin0) * istep;
    int b0 = (int)ceilf(kf - w);
    int b1 = (int)floorf(kf + w);
    int fs = max(b1 + 1, 0);
    if (fs <= 31) atomicAdd(&cnt[fs][t], isn);
    float q = Cl * kf;
    float fsn = (float)isn;
    int blo = max(b0, 0), bhi = min(b1, 31);
    for (int b = blo; b <= bhi; ++b) {
      float e2 = __builtin_amdgcn_exp2f(fmaf(-Cl, (float)b, q));
      float val = fsn * __builtin_amdgcn_rcpf(1.f + e2);
      atomicAdd(&acc[b][t], (int)rintf(val * FPS));
    }
  }
  __syncthreads();
  int gb = g << 10;
  for (int i = tid; i < 1024; i += 256) {
    int vc = ((int*)cnt)[i];
    if (vc) atomicAdd(&gcnt[gb + i], vc);
    int va = ((int*)acc)[i];
    if (va) atomicAdd(&gacc[gb + i], va);
  }
}

// K4: per-graph: prefix-sum markers over bins (Hillis-Steele), add fractional
// part, max over (bin,theta), normalize, write out.
__global__ __launch_bounds__(1024) void fin_kernel(const int* __restrict__ gcnt,
    const int* __restrict__ gacc, float* __restrict__ out) {
  __shared__ float s[32][33];
  __shared__ float wmax[16];
  int g = blockIdx.x, tid = threadIdx.x;
  int k = tid >> 5, t = tid & 31;
  s[k][t] = (float)gcnt[(g << 10) + tid];
  __syncthreads();
#pragma unroll
  for (int st = 1; st < 32; st <<= 1) {
    float add = (k >= st) ? s[k - st][t] : 0.f;
    __syncthreads();
    s[k][t] += add;
    __syncthreads();
  }
  float r = s[k][t] + (float)gacc[(g << 10) + tid] * (1.f / FPS);
  float m = r;
#pragma unroll
  for (int off = 32; off > 0; off >>= 1) m = fmaxf(m, __shfl_down(m, off));
  if ((tid & 63) == 0) wmax[tid >> 6] = m;
  __syncthreads();
  if (tid == 0) {
    float mm = wmax[0];
#pragma unroll
    for (int ww = 1; ww < 16; ++ww) mm = fmaxf(mm, wmax[ww]);
    wmax[0] = mm;
  }
  __syncthreads();
  out[(size_t)g * 1024 + tid] = r / wmax[0];
}

extern "C" void kernel_launch(void* const* d_in, const int* in_sizes, int n_in,
                              void* d_out, int out_size, void* d_ws, size_t ws_size,
                              hipStream_t stream) {
  const float* x     = (const float*)d_in[0];
  const float* v     = (const float*)d_in[1];
  const float* lin   = (const float*)d_in[2];
  const int*   ei    = (const int*)d_in[3];
  const int*   face  = (const int*)d_in[4];
  const int*   batch = (const int*)d_in[5];
  const int*   scale = (const int*)d_in[6];
  const int N = in_sizes[5];
  const int E = in_sizes[3] / 2;
  const int F = in_sizes[4] / 3;
  const int M = N + E + F;

  float* nh     = (float*)d_ws;                   // N*32 f32
  int*   sorted = (int*)(nh + (size_t)N * 32);    // 8*M ints (per-graph buckets)
  int*   gcnt   = sorted + (size_t)8 * M;         // 8*1024
  int*   gacc   = gcnt + 8 * 1024;                // 8*1024
  int*   cnt8   = gacc + 8 * 1024;                // 8

  hipMemsetAsync(gcnt, 0, (8 * 1024 * 2 + 8) * sizeof(int), stream);
  nh_kernel<<<(N + 255) / 256, 256, 0, stream>>>(x, v, nh, N);
  scatter_kernel<<<(M + 255) / 256, 256, 0, stream>>>(ei, face, batch, sorted,
                                                      cnt8, N, E, F, M);
  const int grid_ect = (M + CHUNK - 1) / CHUNK + 8;
  ect_kernel<<<grid_ect, 256, 0, stream>>>(nh, ei, face, sorted, cnt8, lin,
                                           scale, gcnt, gacc, N, E, F, M);
  fin_kernel<<<8, 1024, 0, stream>>>(gcnt, gacc, (float*)d_out);
}